// Round 11
// baseline (719.129 us; speedup 1.0000x reference)
//
#include <hip/hip_runtime.h>
#include <hip/hip_bf16.h>
#include <hip/hip_cooperative_groups.h>
#include <math.h>

namespace cg = cooperative_groups;

// N=50000, E=800000, D_IN=64, D_HID=128, D_OUT=64
// R11: cooperative megakernel = R9 phases + grid.sync between them.
//   B: count|cvt|prep -> C: scan_a -> D: scan_c -> E: fill ->
//   F: gather1 -> G: layer1 -> H: layer2 -> I: gather2+log_softmax.
// Grid sized via occupancy query; checked launch; fallback = 8 separate
// kernels (same device code) if the cooperative launch is rejected.

typedef unsigned short u16;
typedef unsigned int   u32;
typedef __attribute__((ext_vector_type(8))) __bf16 bf16x8;
typedef __attribute__((ext_vector_type(4))) float  f32x4;

__device__ __forceinline__ u16 f2bf(float f) {            // RNE fp32->bf16
    u32 u = __float_as_uint(f);
    u32 r = (u + 0x7FFFu + ((u >> 16) & 1u)) >> 16;
    return (u16)r;
}
__device__ __forceinline__ float bfl(u32 u) { return __uint_as_float(u << 16); }
__device__ __forceinline__ float bfh(u32 u) { return __uint_as_float(u & 0xFFFF0000u); }
__device__ __forceinline__ u32 pack2(float a, float b) {
    return (u32)f2bf(a) | ((u32)f2bf(b) << 16);
}

__device__ __forceinline__ int wave_incl_scan(int v, int lane)
{
#pragma unroll
    for (int d = 1; d < 64; d <<= 1) {
        int u = __shfl_up(v, d, 64);
        if (lane >= d) v += u;
    }
    return v;
}

struct MegaParams {
    const float* x;
    const int*   src;
    const int*   dst;
    const float* Wl1; const float* bl1; const float* Wr1;
    const float* Wl2; const float* bl2; const float* Wr2;
    int* cnt; int* off; int* cur; int* bsum;
    u16* perm;
    u16* xb; u16* aggb; u16* hb; u16* m2b;
    u16* W1c; u16* W2c;
    float* out;
    int N, E, B, N8, CB, VB, nCvt8;
    float invN8;
};

// Wave gather core (R8-proven). All __shfl executed by ALL 64 lanes.
__device__ __forceinline__ void gather_core(
    const u32* __restrict__ feat2, const u16* __restrict__ perm,
    int lo, int hi, int lane, int quarter, int c, float acc[4])
{
    float a0 = 0.f, a1 = 0.f, a2 = 0.f, a3 = 0.f;
    float b0 = 0.f, b1 = 0.f, b2 = 0.f, b3 = 0.f;
    for (int base = lo; base < hi; base += 64) {
        int rem = min(64, hi - base);
        int pidx = (lane < rem) ? (int)perm[base + lane] : 0;
        int j = 0;
        for (; j + 8 <= rem; j += 8) {
            int r0 = __shfl(pidx, j + quarter, 64);
            int r1 = __shfl(pidx, j + 4 + quarter, 64);
            uint2 u0 = *(const uint2*)(feat2 + (size_t)r0 * 32 + c * 2);
            uint2 u1 = *(const uint2*)(feat2 + (size_t)r1 * 32 + c * 2);
            a0 += bfl(u0.x); a1 += bfh(u0.x); a2 += bfl(u0.y); a3 += bfh(u0.y);
            b0 += bfl(u1.x); b1 += bfh(u1.x); b2 += bfl(u1.y); b3 += bfh(u1.y);
        }
        for (; j + 4 <= rem; j += 4) {
            int r0 = __shfl(pidx, j + quarter, 64);
            uint2 u0 = *(const uint2*)(feat2 + (size_t)r0 * 32 + c * 2);
            a0 += bfl(u0.x); a1 += bfh(u0.x); a2 += bfl(u0.y); a3 += bfh(u0.y);
        }
        int rr = j + quarter;
        int r0 = __shfl(pidx, rr & 63, 64);   // uniform shfl
        if (rr < rem) {
            uint2 u0 = *(const uint2*)(feat2 + (size_t)r0 * 32 + c * 2);
            a0 += bfl(u0.x); a1 += bfh(u0.x); a2 += bfl(u0.y); a3 += bfh(u0.y);
        }
    }
    acc[0] = a0 + b0; acc[1] = a1 + b1; acc[2] = a2 + b2; acc[3] = a3 + b3;
}

// ---------------------------------------------------------------------------
// Phase device functions (grid-stride over virtual blocks / waves).

__device__ __forceinline__ void phaseB(const MegaParams& p, int vb0, int vbs)
{
    int tid = threadIdx.x;
    int totVB = p.CB + p.VB + 64;
    for (int vb = vb0; vb < totVB; vb += vbs) {
        if (vb < p.CB) {
            int e0 = vb * 2048 + tid * 8;
            if (e0 + 8 <= p.E) {
                int4 d0 = *(const int4*)(p.dst + e0);
                int4 d1 = *(const int4*)(p.dst + e0 + 4);
                atomicAdd(&p.cnt[d0.x], 1); atomicAdd(&p.cnt[d0.y], 1);
                atomicAdd(&p.cnt[d0.z], 1); atomicAdd(&p.cnt[d0.w], 1);
                atomicAdd(&p.cnt[d1.x], 1); atomicAdd(&p.cnt[d1.y], 1);
                atomicAdd(&p.cnt[d1.z], 1); atomicAdd(&p.cnt[d1.w], 1);
            } else {
                for (int e = e0; e < p.E; e++) atomicAdd(&p.cnt[p.dst[e]], 1);
            }
        } else if (vb < p.CB + p.VB) {
            int i = (vb - p.CB) * 256 + tid;
            if (i < p.nCvt8) {
                float4 v0 = ((const float4*)p.x)[i * 2];
                float4 v1 = ((const float4*)p.x)[i * 2 + 1];
                uint4 q;
                q.x = pack2(v0.x, v0.y); q.y = pack2(v0.z, v0.w);
                q.z = pack2(v1.x, v1.y); q.w = pack2(v1.z, v1.w);
                ((uint4*)p.xb)[i] = q;
            }
        } else {
            int i = (vb - p.CB - p.VB) * 256 + tid;
            if (i < 128 * 128) {
                int o = i >> 7, k = i & 127;
                float w1 = (k < 64) ? p.Wr1[o * 64 + k] : p.Wl1[o * 64 + (k - 64)];
                p.W1c[i] = f2bf(w1);
                float w2 = (o < 64) ? p.Wl2[o * 128 + k] : p.Wr2[(o - 64) * 128 + k];
                p.W2c[i] = f2bf(w2);
            }
        }
    }
}

__device__ __forceinline__ void phaseC(const MegaParams& p, int vb0, int vbs,
                                       int* wsum)
{
    int tid = threadIdx.x, lane = tid & 63, wv = tid >> 6;
    for (int vb = vb0; vb < p.B; vb += vbs) {
        int g0 = vb * 1024 + tid * 4;
        int s = 0;
#pragma unroll
        for (int j = 0; j < 4; j++) s += (g0 + j < p.N) ? p.cnt[g0 + j] : 0;
#pragma unroll
        for (int d = 32; d; d >>= 1) s += __shfl_xor(s, d, 64);
        if (lane == 0) wsum[wv] = s;
        __syncthreads();
        if (tid == 0) p.bsum[vb] = wsum[0] + wsum[1] + wsum[2] + wsum[3];
        __syncthreads();
    }
}

__device__ __forceinline__ void phaseD(const MegaParams& p, int vb0, int vbs,
                                       int* wsum)
{
    int tid = threadIdx.x, lane = tid & 63, wv = tid >> 6;
    for (int vb = vb0; vb < p.B; vb += vbs) {
        int boff = 0;
        for (int i = 0; i < vb; i++) boff += p.bsum[i];
        int g0 = vb * 1024 + tid * 4;
        int v[4];
        int s = 0;
#pragma unroll
        for (int j = 0; j < 4; j++) {
            v[j] = (g0 + j < p.N) ? p.cnt[g0 + j] : 0;
            s += v[j];
        }
        int incl = wave_incl_scan(s, lane);
        if (lane == 63) wsum[wv] = incl;
        __syncthreads();
        int woff = 0;
        for (int i = 0; i < wv; i++) woff += wsum[i];
        int run = incl - s + woff + boff;
#pragma unroll
        for (int j = 0; j < 4; j++) {
            if (g0 + j < p.N) { p.off[g0 + j] = run; p.cur[g0 + j] = run; }
            run += v[j];
        }
        if (vb == p.B - 1 && tid == 255) p.off[p.N] = run;
        __syncthreads();
    }
}

__device__ __forceinline__ void phaseE(const MegaParams& p, int vb0, int vbs)
{
    int tid = threadIdx.x;
    int chunks = (p.E + 2047) / 2048;
    int totVB = chunks * 8;
    for (int vb = vb0; vb < totVB; vb += vbs) {
        int g = vb & 7;
        int e0 = (vb >> 3) * 2048 + tid * 8;
        int d[8];
        if (e0 + 8 <= p.E) {
            int4 d0 = *(const int4*)(p.dst + e0);
            int4 d1 = *(const int4*)(p.dst + e0 + 4);
            d[0] = d0.x; d[1] = d0.y; d[2] = d0.z; d[3] = d0.w;
            d[4] = d1.x; d[5] = d1.y; d[6] = d1.z; d[7] = d1.w;
        } else {
            for (int k = 0; k < 8; k++) d[k] = (e0 + k < p.E) ? p.dst[e0 + k] : -1;
        }
#pragma unroll
        for (int k = 0; k < 8; k++) {
            int dd = d[k];
            if (dd < 0) continue;
            int b = (int)((float)dd * p.invN8);
            if (dd >= (b + 1) * p.N8) b++;
            else if (dd < b * p.N8) b--;
            if (b != g) continue;
            int pos = atomicAdd(&p.cur[dd], 1);
            p.perm[pos] = (u16)p.src[e0 + k];
        }
    }
}

__device__ __forceinline__ void phaseF(const MegaParams& p, int w0, int ws)
{
    int lane = threadIdx.x & 63;
    int quarter = lane >> 4, c = lane & 15;
    for (int wid = w0; wid < p.N; wid += ws) {
        int lo = p.off[wid], hi = p.off[wid + 1];
        float acc[4];
        gather_core((const u32*)p.xb, p.perm, lo, hi, lane, quarter, c, acc);
#pragma unroll
        for (int t = 0; t < 4; t++) {
            acc[t] += __shfl_xor(acc[t], 16, 64);
            acc[t] += __shfl_xor(acc[t], 32, 64);
        }
        if (quarter == 0) {
            float inv = 1.f / fmaxf((float)(hi - lo), 1.f);
            uint2 q;
            q.x = pack2(acc[0] * inv, acc[1] * inv);
            q.y = pack2(acc[2] * inv, acc[3] * inv);
            *(uint2*)((u32*)p.aggb + (size_t)wid * 32 + c * 2) = q;
        }
    }
}

__device__ __forceinline__ void phaseG(const MegaParams& p, int vb0, int vbs)
{
    int tid = threadIdx.x;
    int wv = tid >> 6, lane = tid & 63;
    int quad = lane >> 4, l16 = lane & 15;
    int NG = (p.N + 63) / 64;
    for (int vb = vb0; vb < NG; vb += vbs) {
        int node = vb * 64 + wv * 16 + l16;
        int nc = min(node, p.N - 1);
        const u16* xrow = p.xb   + (size_t)nc * 64;
        const u16* arow = p.aggb + (size_t)nc * 64;
        bf16x8 a0 = *(const bf16x8*)(xrow + quad * 8);
        bf16x8 a1 = *(const bf16x8*)(xrow + 32 + quad * 8);
        bf16x8 a2 = *(const bf16x8*)(arow + quad * 8);
        bf16x8 a3 = *(const bf16x8*)(arow + 32 + quad * 8);
        int orow = vb * 64 + wv * 16 + quad * 4;
#pragma unroll
        for (int nt = 0; nt < 8; nt++) {
            const u16* wrow = p.W1c + (size_t)(nt * 16 + l16) * 128 + quad * 8;
            f32x4 acc = {0.f, 0.f, 0.f, 0.f};
            acc = __builtin_amdgcn_mfma_f32_16x16x32_bf16(a0, *(const bf16x8*)(wrow),      acc, 0, 0, 0);
            acc = __builtin_amdgcn_mfma_f32_16x16x32_bf16(a1, *(const bf16x8*)(wrow + 32), acc, 0, 0, 0);
            acc = __builtin_amdgcn_mfma_f32_16x16x32_bf16(a2, *(const bf16x8*)(wrow + 64), acc, 0, 0, 0);
            acc = __builtin_amdgcn_mfma_f32_16x16x32_bf16(a3, *(const bf16x8*)(wrow + 96), acc, 0, 0, 0);
            int oc = nt * 16 + l16;
            float bias = p.bl1[oc];
#pragma unroll
            for (int r = 0; r < 4; r++) {
                int nn = orow + r;
                if (nn < p.N) p.hb[(size_t)nn * 128 + oc] = f2bf(tanhf(acc[r] + bias));
            }
        }
    }
}

__device__ __forceinline__ void phaseH(const MegaParams& p, int vb0, int vbs)
{
    int tid = threadIdx.x;
    int wv = tid >> 6, lane = tid & 63;
    int quad = lane >> 4, l16 = lane & 15;
    int NG = (p.N + 63) / 64;
    for (int vb = vb0; vb < NG; vb += vbs) {
        int node = vb * 64 + wv * 16 + l16;
        int nc = min(node, p.N - 1);
        const u16* hrow = p.hb + (size_t)nc * 128;
        bf16x8 h0 = *(const bf16x8*)(hrow + quad * 8);
        bf16x8 h1 = *(const bf16x8*)(hrow + 32 + quad * 8);
        bf16x8 h2 = *(const bf16x8*)(hrow + 64 + quad * 8);
        bf16x8 h3 = *(const bf16x8*)(hrow + 96 + quad * 8);
        int orow = vb * 64 + wv * 16 + quad * 4;
#pragma unroll
        for (int nt = 0; nt < 8; nt++) {
            const u16* wrow = p.W2c + (size_t)(nt * 16 + l16) * 128 + quad * 8;
            f32x4 acc = {0.f, 0.f, 0.f, 0.f};
            acc = __builtin_amdgcn_mfma_f32_16x16x32_bf16(h0, *(const bf16x8*)(wrow),      acc, 0, 0, 0);
            acc = __builtin_amdgcn_mfma_f32_16x16x32_bf16(h1, *(const bf16x8*)(wrow + 32), acc, 0, 0, 0);
            acc = __builtin_amdgcn_mfma_f32_16x16x32_bf16(h2, *(const bf16x8*)(wrow + 64), acc, 0, 0, 0);
            acc = __builtin_amdgcn_mfma_f32_16x16x32_bf16(h3, *(const bf16x8*)(wrow + 96), acc, 0, 0, 0);
            int oc = nt * 16 + l16;
#pragma unroll
            for (int r = 0; r < 4; r++) {
                int nn = orow + r;
                if (nn >= p.N) continue;
                if (oc < 64) p.m2b[(size_t)nn * 64 + oc] = f2bf(acc[r]);
                else         p.out[(size_t)nn * 64 + (oc - 64)] = acc[r] + p.bl2[oc - 64];
            }
        }
    }
}

__device__ __forceinline__ void phaseI(const MegaParams& p, int w0, int ws)
{
    int lane = threadIdx.x & 63;
    int quarter = lane >> 4, c = lane & 15;
    for (int wid = w0; wid < p.N; wid += ws) {
        int lo = p.off[wid], hi = p.off[wid + 1];
        float acc[4];
        gather_core((const u32*)p.m2b, p.perm, lo, hi, lane, quarter, c, acc);
#pragma unroll
        for (int t = 0; t < 4; t++) {
            acc[t] += __shfl_xor(acc[t], 16, 64);
            acc[t] += __shfl_xor(acc[t], 32, 64);
        }
        float inv = 1.f / fmaxf((float)(hi - lo), 1.f);
        float4 r2 = ((const float4*)(p.out + (size_t)wid * 64))[c];
        float v0 = acc[0] * inv + r2.x;
        float v1 = acc[1] * inv + r2.y;
        float v2 = acc[2] * inv + r2.z;
        float v3 = acc[3] * inv + r2.w;
        float m = fmaxf(fmaxf(v0, v1), fmaxf(v2, v3));
#pragma unroll
        for (int o = 1; o < 16; o <<= 1) m = fmaxf(m, __shfl_xor(m, o, 64));
        float sum = expf(v0 - m) + expf(v1 - m) + expf(v2 - m) + expf(v3 - m);
#pragma unroll
        for (int o = 1; o < 16; o <<= 1) sum += __shfl_xor(sum, o, 64);
        if (quarter == 0) {
            float ls = m + logf(sum);
            float4 res = make_float4(v0 - ls, v1 - ls, v2 - ls, v3 - ls);
            ((float4*)(p.out + (size_t)wid * 64))[c] = res;
        }
    }
}

// ---------------------------------------------------------------------------
__global__ __launch_bounds__(256, 4) void mega_kernel(MegaParams p)
{
    cg::grid_group grid = cg::this_grid();
    __shared__ int wsum[4];
    const int blk = blockIdx.x, nBlk = gridDim.x;
    const int gwave = blk * 4 + (threadIdx.x >> 6);
    const int nWave = nBlk * 4;

    phaseB(p, blk, nBlk);          grid.sync();
    phaseC(p, blk, nBlk, wsum);    grid.sync();
    phaseD(p, blk, nBlk, wsum);    grid.sync();
    phaseE(p, blk, nBlk);          grid.sync();
    phaseF(p, gwave, nWave);       grid.sync();
    phaseG(p, blk, nBlk);          grid.sync();
    phaseH(p, blk, nBlk);          grid.sync();
    phaseI(p, gwave, nWave);
}

// Fallback wrappers (separate launches, no grid.sync needed).
__global__ __launch_bounds__(256) void kB(MegaParams p) { phaseB(p, blockIdx.x, gridDim.x); }
__global__ __launch_bounds__(256) void kC(MegaParams p) { __shared__ int w[4]; phaseC(p, blockIdx.x, gridDim.x, w); }
__global__ __launch_bounds__(256) void kD(MegaParams p) { __shared__ int w[4]; phaseD(p, blockIdx.x, gridDim.x, w); }
__global__ __launch_bounds__(256) void kE(MegaParams p) { phaseE(p, blockIdx.x, gridDim.x); }
__global__ __launch_bounds__(256) void kF(MegaParams p) { phaseF(p, blockIdx.x * 4 + (threadIdx.x >> 6), gridDim.x * 4); }
__global__ __launch_bounds__(256) void kG(MegaParams p) { phaseG(p, blockIdx.x, gridDim.x); }
__global__ __launch_bounds__(256) void kH(MegaParams p) { phaseH(p, blockIdx.x, gridDim.x); }
__global__ __launch_bounds__(256) void kI(MegaParams p) { phaseI(p, blockIdx.x * 4 + (threadIdx.x >> 6), gridDim.x * 4); }

// ---------------------------------------------------------------------------
extern "C" void kernel_launch(void* const* d_in, const int* in_sizes, int n_in,
                              void* d_out, int out_size, void* d_ws, size_t ws_size,
                              hipStream_t stream)
{
    MegaParams p;
    p.x   = (const float*)d_in[0];
    const int* ei = (const int*)d_in[1];
    p.Wl1 = (const float*)d_in[2];
    p.bl1 = (const float*)d_in[3];
    p.Wr1 = (const float*)d_in[4];
    p.Wl2 = (const float*)d_in[5];
    p.bl2 = (const float*)d_in[6];
    p.Wr2 = (const float*)d_in[7];
    p.out = (float*)d_out;

    p.N = in_sizes[0] / 64;   // 50000
    p.E = in_sizes[1] / 2;    // 800000
    p.src = ei;
    p.dst = ei + p.E;
    p.B = (p.N + 1023) / 1024;
    p.N8 = (p.N + 7) / 8;
    p.invN8 = 1.0f / (float)p.N8;
    p.CB = (p.E + 2047) / 2048;
    p.nCvt8 = p.N * 64 / 8;
    p.VB = (p.nCvt8 + 255) / 256;

    // Workspace layout.
    char* wsb = (char*)d_ws;
    size_t npad = ((size_t)p.N + 64) & ~(size_t)63;
    p.cnt  = (int*)wsb;                          // [N]
    p.off  = p.cnt + npad;                       // [N+1]
    p.cur  = p.off + npad;                       // [N]
    p.bsum = p.cur + npad;                       // [<=1024]
    int* bOff = p.bsum + 1024;                   // (layout spacer)
    p.perm = (u16*)(bOff + 1024);                // [E] u16
    size_t epad = ((size_t)p.E + 63) & ~(size_t)63;
    p.xb   = p.perm + epad;                      // [N*64]  bf16
    p.aggb = p.xb + (size_t)p.N * 64;            // [N*64]  bf16
    p.hb   = p.aggb + (size_t)p.N * 64;          // [N*128] bf16
    p.m2b  = p.hb + (size_t)p.N * 128;           // [N*64]  bf16
    p.W1c  = p.m2b + (size_t)p.N * 64;           // [128*128]
    p.W2c  = p.W1c + 128 * 128;                  // [128*128]

    hipMemsetAsync(p.cnt, 0, (size_t)p.N * sizeof(int), stream);

    // Size the cooperative grid from actual occupancy (host-side query,
    // graph-capture-safe; runs once at capture).
    int bpc = 0;
    hipError_t qerr = hipOccupancyMaxActiveBlocksPerMultiprocessor(
        &bpc, mega_kernel, 256, 0);
    int nCU = 0;
    int dev = 0;
    hipGetDevice(&dev);
    hipDeviceGetAttribute(&nCU, hipDeviceAttributeMultiprocessorCount, dev);
    int grid = (qerr == hipSuccess && bpc > 0 && nCU > 0) ? bpc * nCU : 512;

    void* args[] = { &p };
    hipError_t lerr = hipLaunchCooperativeKernel(
        (const void*)mega_kernel, dim3(grid), dim3(256), args, 0, stream);

    if (lerr != hipSuccess) {
        // Fallback: sequential phase kernels (stream-ordered = implicit sync).
        int chunks = (p.E + 2047) / 2048;
        kB<<<p.CB + p.VB + 64, 256, 0, stream>>>(p);
        kC<<<p.B, 256, 0, stream>>>(p);
        kD<<<p.B, 256, 0, stream>>>(p);
        kE<<<chunks * 8, 256, 0, stream>>>(p);
        kF<<<(p.N + 3) / 4, 256, 0, stream>>>(p);
        kG<<<(p.N + 63) / 64, 256, 0, stream>>>(p);
        kH<<<(p.N + 63) / 64, 256, 0, stream>>>(p);
        kI<<<(p.N + 3) / 4, 256, 0, stream>>>(p);
    }
}

// Round 12
// 250.436 us; speedup vs baseline: 2.8715x; 2.8715x over previous
//
#include <hip/hip_runtime.h>
#include <hip/hip_bf16.h>
#include <math.h>

// N=50000, E=800000, D_IN=64, D_HID=128, D_OUT=64
// R12 = R9 pipeline (proven 252 us) + 4-deep MLP in gather_core.
// 9 dispatches: memset, misc(count|cvt|prep), scan_a, scan_c, fill,
//               gather1, layer1, layer2, gather2+logsoftmax.

typedef unsigned short u16;
typedef unsigned int   u32;
typedef __attribute__((ext_vector_type(8))) __bf16 bf16x8;
typedef __attribute__((ext_vector_type(4))) float  f32x4;

__device__ __forceinline__ u16 f2bf(float f) {            // RNE fp32->bf16
    u32 u = __float_as_uint(f);
    u32 r = (u + 0x7FFFu + ((u >> 16) & 1u)) >> 16;
    return (u16)r;
}
__device__ __forceinline__ float bfl(u32 u) { return __uint_as_float(u << 16); }
__device__ __forceinline__ float bfh(u32 u) { return __uint_as_float(u & 0xFFFF0000u); }
__device__ __forceinline__ u32 pack2(float a, float b) {
    return (u32)f2bf(a) | ((u32)f2bf(b) << 16);
}

// ---------------------------------------------------------------------------
// Fused misc kernel: blocks [0,CB) count dst histogram (int4, 8 edges/thread);
// blocks [CB,CB+VB) cvt x->bf16 (8 elems/thread); blocks [CB+VB, +64) pack W.
__global__ __launch_bounds__(256) void misc_kernel(
    const int* __restrict__ dst, int* __restrict__ cnt, int E,
    const float* __restrict__ x, uint4* __restrict__ xb4, int nCvt8,
    const float* __restrict__ Wl1, const float* __restrict__ Wr1,
    const float* __restrict__ Wl2, const float* __restrict__ Wr2,
    u16* __restrict__ W1c, u16* __restrict__ W2c, int CB, int VB)
{
    int blk = blockIdx.x, tid = threadIdx.x;
    if (blk < CB) {
        int e0 = blk * 2048 + tid * 8;
        if (e0 + 8 <= E) {
            int4 d0 = *(const int4*)(dst + e0);
            int4 d1 = *(const int4*)(dst + e0 + 4);
            atomicAdd(&cnt[d0.x], 1); atomicAdd(&cnt[d0.y], 1);
            atomicAdd(&cnt[d0.z], 1); atomicAdd(&cnt[d0.w], 1);
            atomicAdd(&cnt[d1.x], 1); atomicAdd(&cnt[d1.y], 1);
            atomicAdd(&cnt[d1.z], 1); atomicAdd(&cnt[d1.w], 1);
        } else {
            for (int e = e0; e < E; e++) atomicAdd(&cnt[dst[e]], 1);
        }
    } else if (blk < CB + VB) {
        int i = (blk - CB) * 256 + tid;
        if (i < nCvt8) {
            float4 v0 = ((const float4*)x)[i * 2];
            float4 v1 = ((const float4*)x)[i * 2 + 1];
            uint4 p;
            p.x = pack2(v0.x, v0.y); p.y = pack2(v0.z, v0.w);
            p.z = pack2(v1.x, v1.y); p.w = pack2(v1.z, v1.w);
            xb4[i] = p;
        }
    } else {
        int i = (blk - CB - VB) * 256 + tid;
        if (i < 128 * 128) {
            int o = i >> 7, k = i & 127;
            float w1 = (k < 64) ? Wr1[o * 64 + k] : Wl1[o * 64 + (k - 64)];
            W1c[i] = f2bf(w1);
            float w2 = (o < 64) ? Wl2[o * 128 + k] : Wr2[(o - 64) * 128 + k];
            W2c[i] = f2bf(w2);
        }
    }
}

// ---------------------------------------------------------------------------
__device__ __forceinline__ int wave_incl_scan(int v, int lane)
{
#pragma unroll
    for (int d = 1; d < 64; d <<= 1) {
        int u = __shfl_up(v, d, 64);
        if (lane >= d) v += u;
    }
    return v;
}

// Stage A: per-block chunk sums (1024 elements/block).
__global__ __launch_bounds__(256) void scan_a_kernel(
    const int* __restrict__ cnt, int* __restrict__ bsum, int N)
{
    __shared__ int wsum[4];
    int t = threadIdx.x, lane = t & 63, wv = t >> 6;
    int g0 = blockIdx.x * 1024 + t * 4;
    int s = 0;
#pragma unroll
    for (int j = 0; j < 4; j++) s += (g0 + j < N) ? cnt[g0 + j] : 0;
#pragma unroll
    for (int d = 32; d; d >>= 1) s += __shfl_xor(s, d, 64);
    if (lane == 0) wsum[wv] = s;
    __syncthreads();
    if (t == 0) bsum[blockIdx.x] = wsum[0] + wsum[1] + wsum[2] + wsum[3];
}

// Stage C: per-block exclusive scan; block offset from summing bsum prefix.
__global__ __launch_bounds__(256) void scan_c_kernel(
    const int* __restrict__ cnt, const int* __restrict__ bsum,
    int* __restrict__ off, int* __restrict__ cur, int N, int B)
{
    __shared__ int wsum[4];
    int t = threadIdx.x, lane = t & 63, wv = t >> 6;
    int boff = 0;
    for (int i = 0; i < blockIdx.x; i++) boff += bsum[i];
    int g0 = blockIdx.x * 1024 + t * 4;
    int v[4];
    int s = 0;
#pragma unroll
    for (int j = 0; j < 4; j++) {
        v[j] = (g0 + j < N) ? cnt[g0 + j] : 0;
        s += v[j];
    }
    int incl = wave_incl_scan(s, lane);
    if (lane == 63) wsum[wv] = incl;
    __syncthreads();
    int woff = 0;
    for (int i = 0; i < wv; i++) woff += wsum[i];
    int run = incl - s + woff + boff;
#pragma unroll
    for (int j = 0; j < 4; j++) {
        if (g0 + j < N) { off[g0 + j] = run; cur[g0 + j] = run; }
        run += v[j];
    }
    if (blockIdx.x == B - 1 && t == 255) off[N] = run;   // total = E
}

// CSR fill: bucketed (8 node-buckets), int4 dst loads, perm u16.
__global__ __launch_bounds__(256) void fill_kernel(
    const int* __restrict__ src, const int* __restrict__ dst,
    int* __restrict__ cur, u16* __restrict__ perm, int E, int N8, float invN8)
{
    int g = blockIdx.x & 7;
    int e0 = (blockIdx.x >> 3) * 2048 + threadIdx.x * 8;
    int d[8];
    if (e0 + 8 <= E) {
        int4 d0 = *(const int4*)(dst + e0);
        int4 d1 = *(const int4*)(dst + e0 + 4);
        d[0] = d0.x; d[1] = d0.y; d[2] = d0.z; d[3] = d0.w;
        d[4] = d1.x; d[5] = d1.y; d[6] = d1.z; d[7] = d1.w;
    } else {
        for (int k = 0; k < 8; k++) d[k] = (e0 + k < E) ? dst[e0 + k] : -1;
    }
#pragma unroll
    for (int k = 0; k < 8; k++) {
        int dd = d[k];
        if (dd < 0) continue;
        int b = (int)((float)dd * invN8);
        if (dd >= (b + 1) * N8) b++;
        else if (dd < b * N8) b--;
        if (b != g) continue;
        int pos = atomicAdd(&cur[dd], 1);
        perm[pos] = (u16)src[e0 + k];
    }
}

// ---------------------------------------------------------------------------
// Wave gather core: 16 lanes/row (8B = 4 bf16 ch/lane), 4 rows per load
// instruction (quarter = lane>>4). R12: up to FOUR independent loads in
// flight (16 rows/iter), then 8/4/tail. All __shfl executed by ALL 64 lanes
// (uniform control flow); only loads/accumulates are predicated.
__device__ __forceinline__ void gather_core(
    const u32* __restrict__ feat2, const u16* __restrict__ perm,
    int lo, int hi, int lane, int quarter, int c, float acc[4])
{
    float a0 = 0.f, a1 = 0.f, a2 = 0.f, a3 = 0.f;
    float b0 = 0.f, b1 = 0.f, b2 = 0.f, b3 = 0.f;
    float c0 = 0.f, c1 = 0.f, c2 = 0.f, c3 = 0.f;
    float d0 = 0.f, d1 = 0.f, d2 = 0.f, d3 = 0.f;
    for (int base = lo; base < hi; base += 64) {
        int rem = min(64, hi - base);
        int pidx = (lane < rem) ? (int)perm[base + lane] : 0;
        int j = 0;
        for (; j + 16 <= rem; j += 16) {        // 4 loads in flight
            int r0 = __shfl(pidx, j + quarter,      64);
            int r1 = __shfl(pidx, j + 4 + quarter,  64);
            int r2 = __shfl(pidx, j + 8 + quarter,  64);
            int r3 = __shfl(pidx, j + 12 + quarter, 64);
            uint2 u0 = *(const uint2*)(feat2 + (size_t)r0 * 32 + c * 2);
            uint2 u1 = *(const uint2*)(feat2 + (size_t)r1 * 32 + c * 2);
            uint2 u2 = *(const uint2*)(feat2 + (size_t)r2 * 32 + c * 2);
            uint2 u3 = *(const uint2*)(feat2 + (size_t)r3 * 32 + c * 2);
            a0 += bfl(u0.x); a1 += bfh(u0.x); a2 += bfl(u0.y); a3 += bfh(u0.y);
            b0 += bfl(u1.x); b1 += bfh(u1.x); b2 += bfl(u1.y); b3 += bfh(u1.y);
            c0 += bfl(u2.x); c1 += bfh(u2.x); c2 += bfl(u2.y); c3 += bfh(u2.y);
            d0 += bfl(u3.x); d1 += bfh(u3.x); d2 += bfl(u3.y); d3 += bfh(u3.y);
        }
        for (; j + 8 <= rem; j += 8) {          // 2 loads in flight
            int r0 = __shfl(pidx, j + quarter,     64);
            int r1 = __shfl(pidx, j + 4 + quarter, 64);
            uint2 u0 = *(const uint2*)(feat2 + (size_t)r0 * 32 + c * 2);
            uint2 u1 = *(const uint2*)(feat2 + (size_t)r1 * 32 + c * 2);
            a0 += bfl(u0.x); a1 += bfh(u0.x); a2 += bfl(u0.y); a3 += bfh(u0.y);
            b0 += bfl(u1.x); b1 += bfh(u1.x); b2 += bfl(u1.y); b3 += bfh(u1.y);
        }
        for (; j + 4 <= rem; j += 4) {
            int r0 = __shfl(pidx, j + quarter, 64);
            uint2 u0 = *(const uint2*)(feat2 + (size_t)r0 * 32 + c * 2);
            a0 += bfl(u0.x); a1 += bfh(u0.x); a2 += bfl(u0.y); a3 += bfh(u0.y);
        }
        int rr = j + quarter;
        int r0 = __shfl(pidx, rr & 63, 64);     // uniform shfl
        if (rr < rem) {                          // predicate only load/add
            uint2 u0 = *(const uint2*)(feat2 + (size_t)r0 * 32 + c * 2);
            a0 += bfl(u0.x); a1 += bfh(u0.x); a2 += bfl(u0.y); a3 += bfh(u0.y);
        }
    }
    acc[0] = (a0 + b0) + (c0 + d0);
    acc[1] = (a1 + b1) + (c1 + d1);
    acc[2] = (a2 + b2) + (c2 + d2);
    acc[3] = (a3 + b3) + (c3 + d3);
}

// gather1: aggb[n] = bf16( mean of xb[src] rows ). One wave per node.
__global__ __launch_bounds__(256) void gather1_kernel(
    const u32* __restrict__ xb2, const u16* __restrict__ perm,
    const int* __restrict__ off, u32* __restrict__ aggb2, int N)
{
    int wid  = blockIdx.x * 4 + (threadIdx.x >> 6);
    int lane = threadIdx.x & 63;
    if (wid >= N) return;
    int lo = off[wid], hi = off[wid + 1];
    int quarter = lane >> 4, c = lane & 15;
    float acc[4];
    gather_core(xb2, perm, lo, hi, lane, quarter, c, acc);
#pragma unroll
    for (int i = 0; i < 4; i++) {
        acc[i] += __shfl_xor(acc[i], 16, 64);
        acc[i] += __shfl_xor(acc[i], 32, 64);
    }
    if (quarter == 0) {
        float inv = 1.f / fmaxf((float)(hi - lo), 1.f);
        uint2 p;
        p.x = pack2(acc[0] * inv, acc[1] * inv);
        p.y = pack2(acc[2] * inv, acc[3] * inv);
        *(uint2*)(aggb2 + (size_t)wid * 32 + c * 2) = p;
    }
}

// ---------------------------------------------------------------------------
// layer1: hb[n] = bf16( tanh( [xb|aggb] @ W1c^T + b1 ) ), MFMA 16x16x32 bf16.
__global__ __launch_bounds__(256) void layer1_mfma(
    const u16* __restrict__ xb, const u16* __restrict__ aggb,
    const u16* __restrict__ W1, const float* __restrict__ b1,
    u16* __restrict__ hb, int N)
{
    int tid = threadIdx.x;
    int wv = tid >> 6, lane = tid & 63;
    int quad = lane >> 4, l16 = lane & 15;
    int node = blockIdx.x * 64 + wv * 16 + l16;
    int nclamp = min(node, N - 1);
    const u16* xrow = xb   + (size_t)nclamp * 64;
    const u16* arow = aggb + (size_t)nclamp * 64;
    bf16x8 a0 = *(const bf16x8*)(xrow + quad * 8);
    bf16x8 a1 = *(const bf16x8*)(xrow + 32 + quad * 8);
    bf16x8 a2 = *(const bf16x8*)(arow + quad * 8);
    bf16x8 a3 = *(const bf16x8*)(arow + 32 + quad * 8);
    int orow = blockIdx.x * 64 + wv * 16 + quad * 4;
#pragma unroll
    for (int nt = 0; nt < 8; nt++) {
        const u16* wrow = W1 + (size_t)(nt * 16 + l16) * 128 + quad * 8;
        f32x4 acc = {0.f, 0.f, 0.f, 0.f};
        acc = __builtin_amdgcn_mfma_f32_16x16x32_bf16(a0, *(const bf16x8*)(wrow),      acc, 0, 0, 0);
        acc = __builtin_amdgcn_mfma_f32_16x16x32_bf16(a1, *(const bf16x8*)(wrow + 32), acc, 0, 0, 0);
        acc = __builtin_amdgcn_mfma_f32_16x16x32_bf16(a2, *(const bf16x8*)(wrow + 64), acc, 0, 0, 0);
        acc = __builtin_amdgcn_mfma_f32_16x16x32_bf16(a3, *(const bf16x8*)(wrow + 96), acc, 0, 0, 0);
        int oc = nt * 16 + l16;
        float bias = b1[oc];
#pragma unroll
        for (int r = 0; r < 4; r++) {
            int nn = orow + r;
            if (nn < N) hb[(size_t)nn * 128 + oc] = f2bf(tanhf(acc[r] + bias));
        }
    }
}

// layer2: m2b[n] = bf16( hb @ Wl2^T ), r2 (into out) = hb @ Wr2^T + b2.
__global__ __launch_bounds__(256) void layer2_mfma(
    const u16* __restrict__ hb, const u16* __restrict__ W2,
    const float* __restrict__ b2, u16* __restrict__ m2b,
    float* __restrict__ out, int N)
{
    int tid = threadIdx.x;
    int wv = tid >> 6, lane = tid & 63;
    int quad = lane >> 4, l16 = lane & 15;
    int node = blockIdx.x * 64 + wv * 16 + l16;
    int nclamp = min(node, N - 1);
    const u16* hrow = hb + (size_t)nclamp * 128;
    bf16x8 a0 = *(const bf16x8*)(hrow + quad * 8);
    bf16x8 a1 = *(const bf16x8*)(hrow + 32 + quad * 8);
    bf16x8 a2 = *(const bf16x8*)(hrow + 64 + quad * 8);
    bf16x8 a3 = *(const bf16x8*)(hrow + 96 + quad * 8);
    int orow = blockIdx.x * 64 + wv * 16 + quad * 4;
#pragma unroll
    for (int nt = 0; nt < 8; nt++) {
        const u16* wrow = W2 + (size_t)(nt * 16 + l16) * 128 + quad * 8;
        f32x4 acc = {0.f, 0.f, 0.f, 0.f};
        acc = __builtin_amdgcn_mfma_f32_16x16x32_bf16(a0, *(const bf16x8*)(wrow),      acc, 0, 0, 0);
        acc = __builtin_amdgcn_mfma_f32_16x16x32_bf16(a1, *(const bf16x8*)(wrow + 32), acc, 0, 0, 0);
        acc = __builtin_amdgcn_mfma_f32_16x16x32_bf16(a2, *(const bf16x8*)(wrow + 64), acc, 0, 0, 0);
        acc = __builtin_amdgcn_mfma_f32_16x16x32_bf16(a3, *(const bf16x8*)(wrow + 96), acc, 0, 0, 0);
        int oc = nt * 16 + l16;
#pragma unroll
        for (int r = 0; r < 4; r++) {
            int nn = orow + r;
            if (nn >= N) continue;
            if (oc < 64) m2b[(size_t)nn * 64 + oc] = f2bf(acc[r]);
            else         out[(size_t)nn * 64 + (oc - 64)] = acc[r] + b2[oc - 64];
        }
    }
}

// ---------------------------------------------------------------------------
// gather2+final: out[n] = log_softmax( mean(m2b[src]) + r2[n] ). r2 is in out.
__global__ __launch_bounds__(256) void gather2_final_kernel(
    const u32* __restrict__ m2b2, const u16* __restrict__ perm,
    const int* __restrict__ off, float* __restrict__ out, int N)
{
    int wid  = blockIdx.x * 4 + (threadIdx.x >> 6);
    int lane = threadIdx.x & 63;
    if (wid >= N) return;
    int lo = off[wid], hi = off[wid + 1];
    int quarter = lane >> 4, c = lane & 15;
    float acc[4];
    gather_core(m2b2, perm, lo, hi, lane, quarter, c, acc);
#pragma unroll
    for (int i = 0; i < 4; i++) {
        acc[i] += __shfl_xor(acc[i], 16, 64);
        acc[i] += __shfl_xor(acc[i], 32, 64);
    }
    float inv = 1.f / fmaxf((float)(hi - lo), 1.f);
    float4 r2 = ((const float4*)(out + (size_t)wid * 64))[c];
    float v0 = acc[0] * inv + r2.x;
    float v1 = acc[1] * inv + r2.y;
    float v2 = acc[2] * inv + r2.z;
    float v3 = acc[3] * inv + r2.w;
    float m = fmaxf(fmaxf(v0, v1), fmaxf(v2, v3));
#pragma unroll
    for (int o = 1; o < 16; o <<= 1) m = fmaxf(m, __shfl_xor(m, o, 64));
    float sum = expf(v0 - m) + expf(v1 - m) + expf(v2 - m) + expf(v3 - m);
#pragma unroll
    for (int o = 1; o < 16; o <<= 1) sum += __shfl_xor(sum, o, 64);
    if (quarter == 0) {
        float ls = m + logf(sum);
        float4 res = make_float4(v0 - ls, v1 - ls, v2 - ls, v3 - ls);
        ((float4*)(out + (size_t)wid * 64))[c] = res;
    }
}

// ---------------------------------------------------------------------------
extern "C" void kernel_launch(void* const* d_in, const int* in_sizes, int n_in,
                              void* d_out, int out_size, void* d_ws, size_t ws_size,
                              hipStream_t stream)
{
    const float* x   = (const float*)d_in[0];
    const int*   ei  = (const int*)d_in[1];
    const float* Wl1 = (const float*)d_in[2];
    const float* bl1 = (const float*)d_in[3];
    const float* Wr1 = (const float*)d_in[4];
    const float* Wl2 = (const float*)d_in[5];
    const float* bl2 = (const float*)d_in[6];
    const float* Wr2 = (const float*)d_in[7];
    float* out = (float*)d_out;

    int N = in_sizes[0] / 64;   // 50000
    int E = in_sizes[1] / 2;    // 800000
    const int* src = ei;
    const int* dst = ei + E;
    int B = (N + 1023) / 1024;
    int N8 = (N + 7) / 8;
    float invN8 = 1.0f / (float)N8;

    // Workspace layout.
    char* wsb = (char*)d_ws;
    size_t npad = ((size_t)N + 64) & ~(size_t)63;
    int* cnt  = (int*)wsb;                       // [N]
    int* off  = cnt + npad;                      // [N+1]
    int* cur  = off + npad;                      // [N]
    int* bsum = cur + npad;                      // [<=1024]
    int* bOff = bsum + 1024;                     // (layout spacer)
    u16* perm = (u16*)(bOff + 1024);             // [E] u16
    size_t epad = ((size_t)E + 63) & ~(size_t)63;
    u16* xb   = perm + epad;                     // [N*64]  bf16
    u16* aggb = xb + (size_t)N * 64;             // [N*64]  bf16
    u16* hb   = aggb + (size_t)N * 64;           // [N*128] bf16
    u16* m2b  = hb + (size_t)N * 128;            // [N*64]  bf16
    u16* W1c  = m2b + (size_t)N * 64;            // [128*128]
    u16* W2c  = W1c + 128 * 128;                 // [128*128]

    hipMemsetAsync(cnt, 0, (size_t)N * sizeof(int), stream);

    // Fused count | cvt | prep.
    int CB = (E + 2047) / 2048;
    int nCvt8 = N * 64 / 8;
    int VB = (nCvt8 + 255) / 256;
    misc_kernel<<<CB + VB + 64, 256, 0, stream>>>(
        dst, cnt, E, x, (uint4*)xb, nCvt8,
        Wl1, Wr1, Wl2, Wr2, W1c, W2c, CB, VB);

    // Scan (2 stages) + fill.
    scan_a_kernel<<<B, 256, 0, stream>>>(cnt, bsum, N);
    scan_c_kernel<<<B, 256, 0, stream>>>(cnt, bsum, off, cur, N, B);
    {
        int chunks = (E + 2047) / 2048;
        fill_kernel<<<chunks * 8, 256, 0, stream>>>(src, dst, cur, perm, E,
                                                    N8, invN8);
    }

    // Phase 1: aggb = bf16(mean of xb over in-edges).
    gather1_kernel<<<(N + 3) / 4, 256, 0, stream>>>((const u32*)xb, perm, off,
                                                    (u32*)aggb, N);
    // Phase 2: hb = bf16(tanh([xb|aggb] @ W1c^T + b1))
    layer1_mfma<<<(N + 63) / 64, 256, 0, stream>>>(xb, aggb, W1c, bl1, hb, N);

    // Phase 3: m2b = bf16(hb @ Wl2^T); r2 = hb @ Wr2^T + b2 -> out
    layer2_mfma<<<(N + 63) / 64, 256, 0, stream>>>(hb, W2c, bl2, m2b, out, N);

    // Phase 4+5: out = log_softmax(mean(m2b) + r2)
    gather2_final_kernel<<<(N + 3) / 4, 256, 0, stream>>>((const u32*)m2b, perm,
                                                          off, out, N);
}

// Round 13
// 249.526 us; speedup vs baseline: 2.8820x; 1.0036x over previous
//
#include <hip/hip_runtime.h>
#include <hip/hip_bf16.h>
#include <math.h>

// N=50000, E=800000, D_IN=64, D_HID=128, D_OUT=64
// R13 = R12 + padded CSR (segments padded to x16 with sentinel row N that is
// all-zero) -> branchless gather_core (no lane guards, no remainder loops).
// 9 dispatches: memset, misc(count|cvt|prep|permfill|zrow), scan_a, scan_c,
//               fill, gather1, layer1, layer2, gather2+logsoftmax.

typedef unsigned short u16;
typedef unsigned int   u32;
typedef __attribute__((ext_vector_type(8))) __bf16 bf16x8;
typedef __attribute__((ext_vector_type(4))) float  f32x4;

__device__ __forceinline__ u16 f2bf(float f) {            // RNE fp32->bf16
    u32 u = __float_as_uint(f);
    u32 r = (u + 0x7FFFu + ((u >> 16) & 1u)) >> 16;
    return (u16)r;
}
__device__ __forceinline__ float bfl(u32 u) { return __uint_as_float(u << 16); }
__device__ __forceinline__ float bfh(u32 u) { return __uint_as_float(u & 0xFFFF0000u); }
__device__ __forceinline__ u32 pack2(float a, float b) {
    return (u32)f2bf(a) | ((u32)f2bf(b) << 16);
}
__device__ __forceinline__ int pad16(int x) { return (x + 15) & ~15; }

// ---------------------------------------------------------------------------
// Fused misc kernel. Virtual block ranges:
//   [0,CB): dst histogram (int4, 8 edges/thread)
//   [CB,CB+VB): cvt x->bf16 (8 elems/thread)
//   [CB+VB, +64): weight pack
//   [+64, +64+PB): perm pre-fill with sentinel N (8 u16/thread)
//   last block: zero xb row N and m2b row N
__global__ __launch_bounds__(256) void misc_kernel(
    const int* __restrict__ dst, int* __restrict__ cnt, int E,
    const float* __restrict__ x, uint4* __restrict__ xb4, int nCvt8,
    const float* __restrict__ Wl1, const float* __restrict__ Wr1,
    const float* __restrict__ Wl2, const float* __restrict__ Wr2,
    u16* __restrict__ W1c, u16* __restrict__ W2c,
    u16* __restrict__ perm, int permStore8,
    u16* __restrict__ xb, u16* __restrict__ m2b,
    int N, int CB, int VB, int PB)
{
    int blk = blockIdx.x, tid = threadIdx.x;
    if (blk < CB) {
        int e0 = blk * 2048 + tid * 8;
        if (e0 + 8 <= E) {
            int4 d0 = *(const int4*)(dst + e0);
            int4 d1 = *(const int4*)(dst + e0 + 4);
            atomicAdd(&cnt[d0.x], 1); atomicAdd(&cnt[d0.y], 1);
            atomicAdd(&cnt[d0.z], 1); atomicAdd(&cnt[d0.w], 1);
            atomicAdd(&cnt[d1.x], 1); atomicAdd(&cnt[d1.y], 1);
            atomicAdd(&cnt[d1.z], 1); atomicAdd(&cnt[d1.w], 1);
        } else {
            for (int e = e0; e < E; e++) atomicAdd(&cnt[dst[e]], 1);
        }
    } else if (blk < CB + VB) {
        int i = (blk - CB) * 256 + tid;
        if (i < nCvt8) {
            float4 v0 = ((const float4*)x)[i * 2];
            float4 v1 = ((const float4*)x)[i * 2 + 1];
            uint4 p;
            p.x = pack2(v0.x, v0.y); p.y = pack2(v0.z, v0.w);
            p.z = pack2(v1.x, v1.y); p.w = pack2(v1.z, v1.w);
            xb4[i] = p;
        }
    } else if (blk < CB + VB + 64) {
        int i = (blk - CB - VB) * 256 + tid;
        if (i < 128 * 128) {
            int o = i >> 7, k = i & 127;
            float w1 = (k < 64) ? Wr1[o * 64 + k] : Wl1[o * 64 + (k - 64)];
            W1c[i] = f2bf(w1);
            float w2 = (o < 64) ? Wl2[o * 128 + k] : Wr2[(o - 64) * 128 + k];
            W2c[i] = f2bf(w2);
        }
    } else if (blk < CB + VB + 64 + PB) {
        int i = (blk - CB - VB - 64) * 256 + tid;   // uint4 index (8 u16)
        if (i < permStore8) {
            u32 v = (u32)N | ((u32)N << 16);
            uint4 q; q.x = v; q.y = v; q.z = v; q.w = v;
            ((uint4*)perm)[i] = q;
        }
    } else {
        // zero sentinel rows: xb[N], m2b[N] (64 bf16 = 32 u32 each)
        if (tid < 32)      ((u32*)(xb  + (size_t)N * 64))[tid] = 0;
        else if (tid < 64) ((u32*)(m2b + (size_t)N * 64))[tid - 32] = 0;
    }
}

// ---------------------------------------------------------------------------
__device__ __forceinline__ int wave_incl_scan(int v, int lane)
{
#pragma unroll
    for (int d = 1; d < 64; d <<= 1) {
        int u = __shfl_up(v, d, 64);
        if (lane >= d) v += u;
    }
    return v;
}

// Stage A: per-block chunk sums of PADDED counts (1024 elements/block).
__global__ __launch_bounds__(256) void scan_a_kernel(
    const int* __restrict__ cnt, int* __restrict__ bsum, int N)
{
    __shared__ int wsum[4];
    int t = threadIdx.x, lane = t & 63, wv = t >> 6;
    int g0 = blockIdx.x * 1024 + t * 4;
    int s = 0;
#pragma unroll
    for (int j = 0; j < 4; j++) s += (g0 + j < N) ? pad16(cnt[g0 + j]) : 0;
#pragma unroll
    for (int d = 32; d; d >>= 1) s += __shfl_xor(s, d, 64);
    if (lane == 0) wsum[wv] = s;
    __syncthreads();
    if (t == 0) bsum[blockIdx.x] = wsum[0] + wsum[1] + wsum[2] + wsum[3];
}

// Stage C: per-block exclusive scan of PADDED counts + self-computed offset.
__global__ __launch_bounds__(256) void scan_c_kernel(
    const int* __restrict__ cnt, const int* __restrict__ bsum,
    int* __restrict__ off, int* __restrict__ cur, int N, int B)
{
    __shared__ int wsum[4];
    int t = threadIdx.x, lane = t & 63, wv = t >> 6;
    int boff = 0;
    for (int i = 0; i < blockIdx.x; i++) boff += bsum[i];
    int g0 = blockIdx.x * 1024 + t * 4;
    int v[4];
    int s = 0;
#pragma unroll
    for (int j = 0; j < 4; j++) {
        v[j] = (g0 + j < N) ? pad16(cnt[g0 + j]) : 0;
        s += v[j];
    }
    int incl = wave_incl_scan(s, lane);
    if (lane == 63) wsum[wv] = incl;
    __syncthreads();
    int woff = 0;
    for (int i = 0; i < wv; i++) woff += wsum[i];
    int run = incl - s + woff + boff;
#pragma unroll
    for (int j = 0; j < 4; j++) {
        if (g0 + j < N) { off[g0 + j] = run; cur[g0 + j] = run; }
        run += v[j];
    }
    if (blockIdx.x == B - 1 && t == 255) off[N] = run;   // padded total
}

// CSR fill: bucketed (8 node-buckets), int4 dst loads, perm u16.
// Writes cnt[d] real entries per node starting at padded off; pads stay = N.
__global__ __launch_bounds__(256) void fill_kernel(
    const int* __restrict__ src, const int* __restrict__ dst,
    int* __restrict__ cur, u16* __restrict__ perm, int E, int N8, float invN8)
{
    int g = blockIdx.x & 7;
    int e0 = (blockIdx.x >> 3) * 2048 + threadIdx.x * 8;
    int d[8];
    if (e0 + 8 <= E) {
        int4 d0 = *(const int4*)(dst + e0);
        int4 d1 = *(const int4*)(dst + e0 + 4);
        d[0] = d0.x; d[1] = d0.y; d[2] = d0.z; d[3] = d0.w;
        d[4] = d1.x; d[5] = d1.y; d[6] = d1.z; d[7] = d1.w;
    } else {
        for (int k = 0; k < 8; k++) d[k] = (e0 + k < E) ? dst[e0 + k] : -1;
    }
#pragma unroll
    for (int k = 0; k < 8; k++) {
        int dd = d[k];
        if (dd < 0) continue;
        int b = (int)((float)dd * invN8);
        if (dd >= (b + 1) * N8) b++;
        else if (dd < b * N8) b--;
        if (b != g) continue;
        int pos = atomicAdd(&cur[dd], 1);
        perm[pos] = (u16)src[e0 + k];
    }
}

// ---------------------------------------------------------------------------
// Branchless wave gather core. Segments are [lo,hi) with lo,hi multiples of
// 16; entries beyond the real degree are sentinel N -> all-zero feature row.
// 16 lanes/row, 8B/lane, 4 rows/instr (quarter), 4 loads in flight.
// No lane predication anywhere; all shfls uniform.
__device__ __forceinline__ void gather_core(
    const u32* __restrict__ feat2, const u16* __restrict__ perm,
    int lo, int hi, int lane, int quarter, int c, float acc[4])
{
    float a0 = 0.f, a1 = 0.f, a2 = 0.f, a3 = 0.f;
    float b0 = 0.f, b1 = 0.f, b2 = 0.f, b3 = 0.f;
    float c0 = 0.f, c1 = 0.f, c2 = 0.f, c3 = 0.f;
    float d0 = 0.f, d1 = 0.f, d2 = 0.f, d3 = 0.f;
    for (int base = lo; base < hi; base += 64) {
        int pidx = (int)perm[base + lane];      // pads/slack hold N (valid)
        int rem = min(64, hi - base);           // multiple of 16
        for (int j = 0; j < rem; j += 16) {
            int r0 = __shfl(pidx, j + quarter,      64);
            int r1 = __shfl(pidx, j + 4 + quarter,  64);
            int r2 = __shfl(pidx, j + 8 + quarter,  64);
            int r3 = __shfl(pidx, j + 12 + quarter, 64);
            uint2 u0 = *(const uint2*)(feat2 + (size_t)r0 * 32 + c * 2);
            uint2 u1 = *(const uint2*)(feat2 + (size_t)r1 * 32 + c * 2);
            uint2 u2 = *(const uint2*)(feat2 + (size_t)r2 * 32 + c * 2);
            uint2 u3 = *(const uint2*)(feat2 + (size_t)r3 * 32 + c * 2);
            a0 += bfl(u0.x); a1 += bfh(u0.x); a2 += bfl(u0.y); a3 += bfh(u0.y);
            b0 += bfl(u1.x); b1 += bfh(u1.x); b2 += bfl(u1.y); b3 += bfh(u1.y);
            c0 += bfl(u2.x); c1 += bfh(u2.x); c2 += bfl(u2.y); c3 += bfh(u2.y);
            d0 += bfl(u3.x); d1 += bfh(u3.x); d2 += bfl(u3.y); d3 += bfh(u3.y);
        }
    }
    acc[0] = (a0 + b0) + (c0 + d0);
    acc[1] = (a1 + b1) + (c1 + d1);
    acc[2] = (a2 + b2) + (c2 + d2);
    acc[3] = (a3 + b3) + (c3 + d3);
}

// gather1: aggb[n] = bf16( sum(xb[perm]) / max(deg,1) ). One wave per node.
__global__ __launch_bounds__(256) void gather1_kernel(
    const u32* __restrict__ xb2, const u16* __restrict__ perm,
    const int* __restrict__ off, const int* __restrict__ cnt,
    u32* __restrict__ aggb2, int N)
{
    int wid  = blockIdx.x * 4 + (threadIdx.x >> 6);
    int lane = threadIdx.x & 63;
    if (wid >= N) return;
    int lo = off[wid], hi = off[wid + 1];
    int quarter = lane >> 4, c = lane & 15;
    float acc[4];
    gather_core(xb2, perm, lo, hi, lane, quarter, c, acc);
#pragma unroll
    for (int i = 0; i < 4; i++) {
        acc[i] += __shfl_xor(acc[i], 16, 64);
        acc[i] += __shfl_xor(acc[i], 32, 64);
    }
    if (quarter == 0) {
        float inv = 1.f / fmaxf((float)cnt[wid], 1.f);
        uint2 p;
        p.x = pack2(acc[0] * inv, acc[1] * inv);
        p.y = pack2(acc[2] * inv, acc[3] * inv);
        *(uint2*)(aggb2 + (size_t)wid * 32 + c * 2) = p;
    }
}

// ---------------------------------------------------------------------------
// layer1: hb[n] = bf16( tanh( [xb|aggb] @ W1c^T + b1 ) ), MFMA 16x16x32 bf16.
__global__ __launch_bounds__(256) void layer1_mfma(
    const u16* __restrict__ xb, const u16* __restrict__ aggb,
    const u16* __restrict__ W1, const float* __restrict__ b1,
    u16* __restrict__ hb, int N)
{
    int tid = threadIdx.x;
    int wv = tid >> 6, lane = tid & 63;
    int quad = lane >> 4, l16 = lane & 15;
    int node = blockIdx.x * 64 + wv * 16 + l16;
    int nclamp = min(node, N - 1);
    const u16* xrow = xb   + (size_t)nclamp * 64;
    const u16* arow = aggb + (size_t)nclamp * 64;
    bf16x8 a0 = *(const bf16x8*)(xrow + quad * 8);
    bf16x8 a1 = *(const bf16x8*)(xrow + 32 + quad * 8);
    bf16x8 a2 = *(const bf16x8*)(arow + quad * 8);
    bf16x8 a3 = *(const bf16x8*)(arow + 32 + quad * 8);
    int orow = blockIdx.x * 64 + wv * 16 + quad * 4;
#pragma unroll
    for (int nt = 0; nt < 8; nt++) {
        const u16* wrow = W1 + (size_t)(nt * 16 + l16) * 128 + quad * 8;
        f32x4 acc = {0.f, 0.f, 0.f, 0.f};
        acc = __builtin_amdgcn_mfma_f32_16x16x32_bf16(a0, *(const bf16x8*)(wrow),      acc, 0, 0, 0);
        acc = __builtin_amdgcn_mfma_f32_16x16x32_bf16(a1, *(const bf16x8*)(wrow + 32), acc, 0, 0, 0);
        acc = __builtin_amdgcn_mfma_f32_16x16x32_bf16(a2, *(const bf16x8*)(wrow + 64), acc, 0, 0, 0);
        acc = __builtin_amdgcn_mfma_f32_16x16x32_bf16(a3, *(const bf16x8*)(wrow + 96), acc, 0, 0, 0);
        int oc = nt * 16 + l16;
        float bias = b1[oc];
#pragma unroll
        for (int r = 0; r < 4; r++) {
            int nn = orow + r;
            if (nn < N) hb[(size_t)nn * 128 + oc] = f2bf(tanhf(acc[r] + bias));
        }
    }
}

// layer2: m2b[n] = bf16( hb @ Wl2^T ), r2 (into out) = hb @ Wr2^T + b2.
__global__ __launch_bounds__(256) void layer2_mfma(
    const u16* __restrict__ hb, const u16* __restrict__ W2,
    const float* __restrict__ b2, u16* __restrict__ m2b,
    float* __restrict__ out, int N)
{
    int tid = threadIdx.x;
    int wv = tid >> 6, lane = tid & 63;
    int quad = lane >> 4, l16 = lane & 15;
    int node = blockIdx.x * 64 + wv * 16 + l16;
    int nclamp = min(node, N - 1);
    const u16* hrow = hb + (size_t)nclamp * 128;
    bf16x8 a0 = *(const bf16x8*)(hrow + quad * 8);
    bf16x8 a1 = *(const bf16x8*)(hrow + 32 + quad * 8);
    bf16x8 a2 = *(const bf16x8*)(hrow + 64 + quad * 8);
    bf16x8 a3 = *(const bf16x8*)(hrow + 96 + quad * 8);
    int orow = blockIdx.x * 64 + wv * 16 + quad * 4;
#pragma unroll
    for (int nt = 0; nt < 8; nt++) {
        const u16* wrow = W2 + (size_t)(nt * 16 + l16) * 128 + quad * 8;
        f32x4 acc = {0.f, 0.f, 0.f, 0.f};
        acc = __builtin_amdgcn_mfma_f32_16x16x32_bf16(a0, *(const bf16x8*)(wrow),      acc, 0, 0, 0);
        acc = __builtin_amdgcn_mfma_f32_16x16x32_bf16(a1, *(const bf16x8*)(wrow + 32), acc, 0, 0, 0);
        acc = __builtin_amdgcn_mfma_f32_16x16x32_bf16(a2, *(const bf16x8*)(wrow + 64), acc, 0, 0, 0);
        acc = __builtin_amdgcn_mfma_f32_16x16x32_bf16(a3, *(const bf16x8*)(wrow + 96), acc, 0, 0, 0);
        int oc = nt * 16 + l16;
#pragma unroll
        for (int r = 0; r < 4; r++) {
            int nn = orow + r;
            if (nn >= N) continue;
            if (oc < 64) m2b[(size_t)nn * 64 + oc] = f2bf(acc[r]);
            else         out[(size_t)nn * 64 + (oc - 64)] = acc[r] + b2[oc - 64];
        }
    }
}

// ---------------------------------------------------------------------------
// gather2+final: out[n] = log_softmax( sum(m2b[perm])/deg + r2[n] ).
__global__ __launch_bounds__(256) void gather2_final_kernel(
    const u32* __restrict__ m2b2, const u16* __restrict__ perm,
    const int* __restrict__ off, const int* __restrict__ cnt,
    float* __restrict__ out, int N)
{
    int wid  = blockIdx.x * 4 + (threadIdx.x >> 6);
    int lane = threadIdx.x & 63;
    if (wid >= N) return;
    int lo = off[wid], hi = off[wid + 1];
    int quarter = lane >> 4, c = lane & 15;
    float acc[4];
    gather_core(m2b2, perm, lo, hi, lane, quarter, c, acc);
#pragma unroll
    for (int i = 0; i < 4; i++) {
        acc[i] += __shfl_xor(acc[i], 16, 64);
        acc[i] += __shfl_xor(acc[i], 32, 64);
    }
    float inv = 1.f / fmaxf((float)cnt[wid], 1.f);
    float4 r2 = ((const float4*)(out + (size_t)wid * 64))[c];
    float v0 = acc[0] * inv + r2.x;
    float v1 = acc[1] * inv + r2.y;
    float v2 = acc[2] * inv + r2.z;
    float v3 = acc[3] * inv + r2.w;
    float m = fmaxf(fmaxf(v0, v1), fmaxf(v2, v3));
#pragma unroll
    for (int o = 1; o < 16; o <<= 1) m = fmaxf(m, __shfl_xor(m, o, 64));
    float sum = expf(v0 - m) + expf(v1 - m) + expf(v2 - m) + expf(v3 - m);
#pragma unroll
    for (int o = 1; o < 16; o <<= 1) sum += __shfl_xor(sum, o, 64);
    if (quarter == 0) {
        float ls = m + logf(sum);
        float4 res = make_float4(v0 - ls, v1 - ls, v2 - ls, v3 - ls);
        ((float4*)(out + (size_t)wid * 64))[c] = res;
    }
}

// ---------------------------------------------------------------------------
extern "C" void kernel_launch(void* const* d_in, const int* in_sizes, int n_in,
                              void* d_out, int out_size, void* d_ws, size_t ws_size,
                              hipStream_t stream)
{
    const float* x   = (const float*)d_in[0];
    const int*   ei  = (const int*)d_in[1];
    const float* Wl1 = (const float*)d_in[2];
    const float* bl1 = (const float*)d_in[3];
    const float* Wr1 = (const float*)d_in[4];
    const float* Wl2 = (const float*)d_in[5];
    const float* bl2 = (const float*)d_in[6];
    const float* Wr2 = (const float*)d_in[7];
    float* out = (float*)d_out;

    int N = in_sizes[0] / 64;   // 50000
    int E = in_sizes[1] / 2;    // 800000
    const int* src = ei;
    const int* dst = ei + E;
    int B = (N + 1023) / 1024;
    int N8 = (N + 7) / 8;
    float invN8 = 1.0f / (float)N8;

    // Padded perm sizing: worst case E + 15 per node, +64 slack for reads.
    int permN = E + 16 * N + 64;
    int permStore8 = (permN + 7) / 8;            // uint4 stores (8 u16 each)
    int PB = (permStore8 + 255) / 256;

    // Workspace layout.
    char* wsb = (char*)d_ws;
    size_t npad = ((size_t)N + 64) & ~(size_t)63;
    int* cnt  = (int*)wsb;                       // [N] true degrees
    int* off  = cnt + npad;                      // [N+1] padded offsets
    int* cur  = off + npad;                      // [N]
    int* bsum = cur + npad;                      // [<=1024]
    int* bOff = bsum + 1024;                     // (layout spacer)
    u16* perm = (u16*)(bOff + 1024);             // [permN] u16
    size_t ppad = ((size_t)permN + 63) & ~(size_t)63;
    u16* xb   = perm + ppad;                     // [(N+1)*64] bf16 (+zero row)
    u16* aggb = xb + (size_t)(N + 1) * 64;       // [N*64]  bf16
    u16* hb   = aggb + (size_t)N * 64;           // [N*128] bf16
    u16* m2b  = hb + (size_t)N * 128;            // [(N+1)*64] bf16 (+zero row)
    u16* W1c  = m2b + (size_t)(N + 1) * 64;      // [128*128]
    u16* W2c  = W1c + 128 * 128;                 // [128*128]

    hipMemsetAsync(cnt, 0, (size_t)N * sizeof(int), stream);

    // Fused count | cvt | prep | perm-prefill | zero-rows.
    int CB = (E + 2047) / 2048;
    int nCvt8 = N * 64 / 8;
    int VB = (nCvt8 + 255) / 256;
    misc_kernel<<<CB + VB + 64 + PB + 1, 256, 0, stream>>>(
        dst, cnt, E, x, (uint4*)xb, nCvt8,
        Wl1, Wr1, Wl2, Wr2, W1c, W2c,
        perm, permStore8, xb, m2b, N, CB, VB, PB);

    // Scan (2 stages, padded counts) + fill.
    scan_a_kernel<<<B, 256, 0, stream>>>(cnt, bsum, N);
    scan_c_kernel<<<B, 256, 0, stream>>>(cnt, bsum, off, cur, N, B);
    {
        int chunks = (E + 2047) / 2048;
        fill_kernel<<<chunks * 8, 256, 0, stream>>>(src, dst, cur, perm, E,
                                                    N8, invN8);
    }

    // Phase 1: aggb = bf16(mean of xb over in-edges).
    gather1_kernel<<<(N + 3) / 4, 256, 0, stream>>>((const u32*)xb, perm, off,
                                                    cnt, (u32*)aggb, N);
    // Phase 2: hb = bf16(tanh([xb|aggb] @ W1c^T + b1))
    layer1_mfma<<<(N + 63) / 64, 256, 0, stream>>>(xb, aggb, W1c, bl1, hb, N);

    // Phase 3: m2b = bf16(hb @ Wl2^T); r2 = hb @ Wr2^T + b2 -> out
    layer2_mfma<<<(N + 63) / 64, 256, 0, stream>>>(hb, W2c, bl2, m2b, out, N);

    // Phase 4+5: out = log_softmax(mean(m2b) + r2)
    gather2_final_kernel<<<(N + 3) / 4, 256, 0, stream>>>((const u32*)m2b, perm,
                                                          off, cnt, out, N);
}